// Round 11
// baseline (69.939 us; speedup 1.0000x reference)
//
#include <hip/hip_runtime.h>
#include <math.h>

#define Bq 512
#define Nq 128
#define Mq 256
#define Eq 64
#define LOG2E 1.4426950408889634f

typedef float nfloat4 __attribute__((ext_vector_type(4)));

#define DPPADD(X, CTRL) \
    (X) += __int_as_float(__builtin_amdgcn_update_dpp(0, __float_as_int(X), (CTRL), 0xf, 0xf, true));

// Sum across each 32-lane half; result uniform within the half.
__device__ __forceinline__ float halfReduce32(float x) {
    DPPADD(x, 0x0B1)  // quad_perm xor1
    DPPADD(x, 0x04E)  // quad_perm xor2
    DPPADD(x, 0x141)  // row_half_mirror (xor4)
    DPPADD(x, 0x140)  // row_mirror (xor8)
    x += __int_as_float(__builtin_amdgcn_ds_swizzle(__float_as_int(x), 0x401F)); // xor16
    return x;
}

// Non-temporal float4 load (bypass cache allocation for the zero-reuse stream).
// __builtin_nontemporal_load needs a native vector type, not HIP_vector_type.
__device__ __forceinline__ float4 ntload4(const float4* p) {
    nfloat4 v = __builtin_nontemporal_load((const nfloat4*)p);
    return make_float4(v.x, v.y, v.z, v.w);
}

// One distance row S (absolute) from ring slot K; optional refill with row S+8.
// Each 32-lane half holds the FULL 128-float row as float4/lane; all softmax
// scalars are uniform-per-half. a1 uses previous row's weight (wprev).
#define ROWB(K, S, RF)                                                    \
    {                                                                     \
        float4 e = buf[(K)];                                              \
        if (RF) buf[(K)] = ntload4(pr + (size_t)((S) + 8) * 16384);       \
        float d = (fabsf(e.x - zc0.x) + fabsf(e.y - zc0.y)) +             \
                  (fabsf(e.z - zc0.z) + fabsf(e.w - zc0.w));              \
        d = halfReduce32(d);                                              \
        float v = d * negt;                                               \
        float mnew = fmaxf(mrun, v);                                      \
        float sc = exp2f(mrun - mnew);                                    \
        float w  = exp2f(v - mnew);                                       \
        float wp = wprev * sc;                                            \
        mrun = mnew;                                                      \
        Zrun = fmaf(Zrun, sc, w);                                         \
        a0.x = fmaf(a0.x, sc, w * e.x);   a0.y = fmaf(a0.y, sc, w * e.y); \
        a0.z = fmaf(a0.z, sc, w * e.z);   a0.w = fmaf(a0.w, sc, w * e.w); \
        a1.x = fmaf(a1.x, sc, wp * e.x);  a1.y = fmaf(a1.y, sc, wp * e.y);\
        a1.z = fmaf(a1.z, sc, wp * e.z);  a1.w = fmaf(a1.w, sc, wp * e.w);\
        wprev = w;                                                        \
    }

extern "C" __global__ void __launch_bounds__(512, 4)
gating_kernel(const float* __restrict__ context,
              const float* __restrict__ z,
              const float* __restrict__ noise,
              const float* __restrict__ conv_w,
              const float* __restrict__ conv_b,
              const float* __restrict__ D,
              const float* __restrict__ sigma,
              const float* __restrict__ temp1,
              const float* __restrict__ W1,
              const float* __restrict__ b1,
              const float* __restrict__ W2,
              const float* __restrict__ b2,
              const float* __restrict__ temp2,
              float* __restrict__ out)
{
    const int b    = blockIdx.x;
    const int tid  = threadIdx.x;
    const int wave = tid >> 6;
    const int lane = tid & 63;
    const int half = lane >> 5;
    const int l5   = lane & 31;
    const int idx  = wave * 2 + half;          // 16 half-wave states

    __shared__ __align__(16) float sA0[16][128];
    __shared__ __align__(16) float sA1[16][128];
    __shared__ float smx[16];
    __shared__ float sZ[16];
    __shared__ __align__(16) float gA0[128];
    __shared__ __align__(16) float gA1[128];
    __shared__ __align__(16) float semb[128];
    __shared__ __align__(16) float szc[128];
    __shared__ __align__(16) float szcol[256];
    __shared__ __align__(16) float shb[64];

    // half-wave's own 64-row band
    const int myLo = wave * 128 + half * 64;
    const int myHi = min(1023, myLo + 64);     // rows [myLo,myHi); row myHi = a1 tail

    // lane's 16B slice of the 512B row; row stride 16384 float4s
    const float4* pr = (const float4*)context + (size_t)b * 32 + l5;

    // ring preload BEFORE phase 0 (loads fly under the D@z prologue)
    float4 buf[8];
    #pragma unroll
    for (int j = 0; j < 8; ++j)
        buf[j] = ntload4(pr + (size_t)(myLo + j) * 16384);
    float4 xtra = ntload4(pr + (size_t)myHi * 16384);

    // ---- phase 0: stage z column; zc = D @ z + sigma * noise ----
    if (tid < 256) szcol[tid] = z[tid * Bq + b];
    __syncthreads();
    if (tid < 128) {
        const float4* Drow = (const float4*)(D + tid * Mq);
        float c0 = 0.f, c1 = 0.f, c2 = 0.f, c3 = 0.f;
        #pragma unroll 8
        for (int i = 0; i < 64; ++i) {
            float4 dv = Drow[i];
            c0 = fmaf(dv.x, szcol[4 * i + 0], c0);
            c1 = fmaf(dv.y, szcol[4 * i + 1], c1);
            c2 = fmaf(dv.z, szcol[4 * i + 2], c2);
            c3 = fmaf(dv.w, szcol[4 * i + 3], c3);
        }
        szc[tid] = (c0 + c1) + (c2 + c3) + sigma[tid] * noise[tid * Bq + b];
    }
    __syncthreads();

    const float4 zc0 = *(const float4*)&szc[l5 * 4];
    const float negt = -LOG2E / fabsf(temp1[0]);

    float mrun = -INFINITY, Zrun = 0.f, wprev = 0.f;
    float4 a0 = make_float4(0.f, 0.f, 0.f, 0.f);
    float4 a1 = make_float4(0.f, 0.f, 0.f, 0.f);

    // body: refilling batches (refill rows provably <= 1023)
    int rb = myLo;
    for (; rb + 8 < myHi; rb += 8) {
        ROWB(0, rb+0, 1) ROWB(1, rb+1, 1) ROWB(2, rb+2, 1) ROWB(3, rb+3, 1)
        ROWB(4, rb+4, 1) ROWB(5, rb+5, 1) ROWB(6, rb+6, 1) ROWB(7, rb+7, 1)
    }
    // tail: remaining rows rb..myHi-1 resident in slots 0..7
    #pragma unroll
    for (int j = 0; j < 8; ++j) {
        if (rb + j < myHi)
            ROWB(j, rb + j, 0)
    }
    // a1 tail: += w[myHi-1] * ctx[myHi]
    a1.x = fmaf(wprev, xtra.x, a1.x); a1.y = fmaf(wprev, xtra.y, a1.y);
    a1.z = fmaf(wprev, xtra.z, a1.z); a1.w = fmaf(wprev, xtra.w, a1.w);

    // ---- merge 16 half-wave states ----
    *(float4*)&sA0[idx][l5 * 4] = a0;
    *(float4*)&sA1[idx][l5 * 4] = a1;
    if (l5 == 0) { smx[idx] = mrun; sZ[idx] = Zrun; }
    __syncthreads();

    float gm = smx[0];
    #pragma unroll
    for (int k = 1; k < 16; ++k) gm = fmaxf(gm, smx[k]);
    float scl[16];
    float Gz = 0.f;
    #pragma unroll
    for (int k = 0; k < 16; ++k) { scl[k] = exp2f(smx[k] - gm); Gz = fmaf(scl[k], sZ[k], Gz); }

    if (tid < 128) {
        float acc = 0.f;
        #pragma unroll
        for (int k = 0; k < 16; ++k) acc = fmaf(scl[k], sA0[k][tid], acc);
        gA0[tid] = acc;
    } else if (tid < 256) {
        const int t = tid - 128;
        float acc = 0.f;
        #pragma unroll
        for (int k = 0; k < 16; ++k) acc = fmaf(scl[k], sA1[k][t], acc);
        gA1[t] = acc;
    }
    __syncthreads();

    // ---- embedding[o] = (w0[o,:]·A0 + w1[o,:]·A1)/Z + conv_b[o] ----
    if (tid < 128) {
        const float4* wr = (const float4*)(conv_w + tid * 256);
        float acc = 0.f;
        #pragma unroll 8
        for (int i = 0; i < 64; ++i) {
            float4 w4 = wr[i];   // w0[o,2i], w1[o,2i], w0[o,2i+1], w1[o,2i+1]
            acc = fmaf(w4.x, gA0[2 * i], acc);
            acc = fmaf(w4.y, gA1[2 * i], acc);
            acc = fmaf(w4.z, gA0[2 * i + 1], acc);
            acc = fmaf(w4.w, gA1[2 * i + 1], acc);
        }
        semb[tid] = acc / Gz + conv_b[tid];
    }
    __syncthreads();

    // ---- MLP layer 1 ----
    if (tid < 64) {
        const float* w1r = W1 + tid * (Nq + Mq);
        float acc = b1[tid];
        #pragma unroll 8
        for (int i = 0; i < 128; ++i) acc = fmaf(w1r[i], semb[i], acc);
        #pragma unroll 8
        for (int i = 0; i < 256; ++i) acc = fmaf(w1r[128 + i], szcol[i], acc);
        shb[tid] = fmaxf(acc, 0.f);
    }
    __syncthreads();

    // ---- MLP layer 2 + softmax over E ----
    if (tid < 64) {
        const float* w2r = W2 + tid * Eq;
        float acc = b2[tid];
        #pragma unroll 8
        for (int j = 0; j < 64; ++j) acc = fmaf(w2r[j], shb[j], acc);
        float v = -acc * (LOG2E / fabsf(temp2[0]));
        float mx = v;
        #pragma unroll
        for (int off = 32; off > 0; off >>= 1) mx = fmaxf(mx, __shfl_xor(mx, off, 64));
        float w = exp2f(v - mx);
        float s = w;
        #pragma unroll
        for (int off = 32; off > 0; off >>= 1) s += __shfl_xor(s, off, 64);
        out[tid * Bq + b] = w / s;
    }
}

extern "C" void kernel_launch(void* const* d_in, const int* in_sizes, int n_in,
                              void* d_out, int out_size, void* d_ws, size_t ws_size,
                              hipStream_t stream) {
    const float* context = (const float*)d_in[0];
    const float* z       = (const float*)d_in[1];
    const float* noise   = (const float*)d_in[2];
    const float* conv_w  = (const float*)d_in[3];
    const float* conv_b  = (const float*)d_in[4];
    const float* D       = (const float*)d_in[5];
    const float* sigma   = (const float*)d_in[6];
    const float* temp1   = (const float*)d_in[7];
    const float* W1      = (const float*)d_in[8];
    const float* b1      = (const float*)d_in[9];
    const float* W2      = (const float*)d_in[10];
    const float* b2      = (const float*)d_in[11];
    const float* temp2   = (const float*)d_in[12];
    float* out = (float*)d_out;

    gating_kernel<<<dim3(Bq), dim3(512), 0, stream>>>(
        context, z, noise, conv_w, conv_b, D, sigma, temp1,
        W1, b1, W2, b2, temp2, out);
}

// Round 12
// 67.498 us; speedup vs baseline: 1.0362x; 1.0362x over previous
//
#include <hip/hip_runtime.h>
#include <math.h>

#define Bq 512
#define Nq 128
#define Mq 256
#define Eq 64
#define LOG2E 1.4426950408889634f

#define DPPADD(X, CTRL) \
    (X) += __int_as_float(__builtin_amdgcn_update_dpp(0, __float_as_int(X), (CTRL), 0xf, 0xf, true));

// Sum across each 32-lane half; result uniform within the half.
__device__ __forceinline__ float halfReduce32(float x) {
    DPPADD(x, 0x0B1)  // quad_perm xor1
    DPPADD(x, 0x04E)  // quad_perm xor2
    DPPADD(x, 0x141)  // row_half_mirror (xor4)
    DPPADD(x, 0x140)  // row_mirror (xor8)
    x += __int_as_float(__builtin_amdgcn_ds_swizzle(__float_as_int(x), 0x401F)); // xor16
    return x;
}

// One distance row S (absolute) from ring slot K; optional refill with row S+8.
// Each 32-lane half holds the FULL 128-float row as float4/lane; all softmax
// scalars are uniform-per-half. a1 uses previous row's weight (wprev).
#define ROWB(K, S, RF)                                                    \
    {                                                                     \
        float4 e = buf[(K)];                                              \
        if (RF) buf[(K)] = pr[(size_t)((S) + 8) * 16384];                 \
        float d = (fabsf(e.x - zc0.x) + fabsf(e.y - zc0.y)) +             \
                  (fabsf(e.z - zc0.z) + fabsf(e.w - zc0.w));              \
        d = halfReduce32(d);                                              \
        float v = d * negt;                                               \
        float mnew = fmaxf(mrun, v);                                      \
        float sc = exp2f(mrun - mnew);                                    \
        float w  = exp2f(v - mnew);                                       \
        float wp = wprev * sc;                                            \
        mrun = mnew;                                                      \
        Zrun = fmaf(Zrun, sc, w);                                         \
        a0.x = fmaf(a0.x, sc, w * e.x);   a0.y = fmaf(a0.y, sc, w * e.y); \
        a0.z = fmaf(a0.z, sc, w * e.z);   a0.w = fmaf(a0.w, sc, w * e.w); \
        a1.x = fmaf(a1.x, sc, wp * e.x);  a1.y = fmaf(a1.y, sc, wp * e.y);\
        a1.z = fmaf(a1.z, sc, wp * e.z);  a1.w = fmaf(a1.w, sc, wp * e.w);\
        wprev = w;                                                        \
    }

extern "C" __global__ void __launch_bounds__(512, 4)
gating_kernel(const float* __restrict__ context,
              const float* __restrict__ z,
              const float* __restrict__ noise,
              const float* __restrict__ conv_w,
              const float* __restrict__ conv_b,
              const float* __restrict__ D,
              const float* __restrict__ sigma,
              const float* __restrict__ temp1,
              const float* __restrict__ W1,
              const float* __restrict__ b1,
              const float* __restrict__ W2,
              const float* __restrict__ b2,
              const float* __restrict__ temp2,
              float* __restrict__ out)
{
    const int b    = blockIdx.x;
    const int tid  = threadIdx.x;
    const int wave = tid >> 6;
    const int lane = tid & 63;
    const int half = lane >> 5;
    const int l5   = lane & 31;
    const int idx  = wave * 2 + half;          // 16 half-wave states

    __shared__ __align__(16) float sA0[16][128];
    __shared__ __align__(16) float sA1[16][128];
    __shared__ float smx[16];
    __shared__ float sZ[16];
    __shared__ __align__(16) float gA0[128];
    __shared__ __align__(16) float gA1[128];
    __shared__ __align__(16) float semb[128];
    __shared__ __align__(16) float szc[128];
    __shared__ __align__(16) float szcol[256];
    __shared__ __align__(16) float shb[64];

    // half-wave's own 64-row band
    const int myLo = wave * 128 + half * 64;
    const int myHi = min(1023, myLo + 64);     // rows [myLo,myHi); row myHi = a1 tail

    // lane's 16B slice of the 512B row; row stride 16384 float4s
    const float4* pr = (const float4*)context + (size_t)b * 32 + l5;

    // ring preload BEFORE phase 0 (loads fly under the D@z prologue)
    float4 buf[8];
    #pragma unroll
    for (int j = 0; j < 8; ++j)
        buf[j] = pr[(size_t)(myLo + j) * 16384];
    float4 xtra = pr[(size_t)myHi * 16384];

    // ---- phase 0: stage z column; zc = D @ z + sigma * noise ----
    if (tid < 256) szcol[tid] = z[tid * Bq + b];
    __syncthreads();
    if (tid < 128) {
        const float4* Drow = (const float4*)(D + tid * Mq);
        float c0 = 0.f, c1 = 0.f, c2 = 0.f, c3 = 0.f;
        #pragma unroll 8
        for (int i = 0; i < 64; ++i) {
            float4 dv = Drow[i];
            c0 = fmaf(dv.x, szcol[4 * i + 0], c0);
            c1 = fmaf(dv.y, szcol[4 * i + 1], c1);
            c2 = fmaf(dv.z, szcol[4 * i + 2], c2);
            c3 = fmaf(dv.w, szcol[4 * i + 3], c3);
        }
        szc[tid] = (c0 + c1) + (c2 + c3) + sigma[tid] * noise[tid * Bq + b];
    }
    __syncthreads();

    const float4 zc0 = *(const float4*)&szc[l5 * 4];
    const float negt = -LOG2E / fabsf(temp1[0]);

    float mrun = -INFINITY, Zrun = 0.f, wprev = 0.f;
    float4 a0 = make_float4(0.f, 0.f, 0.f, 0.f);
    float4 a1 = make_float4(0.f, 0.f, 0.f, 0.f);

    // body: refilling batches (refill rows provably <= 1023)
    int rb = myLo;
    for (; rb + 8 < myHi; rb += 8) {
        ROWB(0, rb+0, 1) ROWB(1, rb+1, 1) ROWB(2, rb+2, 1) ROWB(3, rb+3, 1)
        ROWB(4, rb+4, 1) ROWB(5, rb+5, 1) ROWB(6, rb+6, 1) ROWB(7, rb+7, 1)
    }
    // tail: remaining rows rb..myHi-1 resident in slots 0..7
    #pragma unroll
    for (int j = 0; j < 8; ++j) {
        if (rb + j < myHi)
            ROWB(j, rb + j, 0)
    }
    // a1 tail: += w[myHi-1] * ctx[myHi]
    a1.x = fmaf(wprev, xtra.x, a1.x); a1.y = fmaf(wprev, xtra.y, a1.y);
    a1.z = fmaf(wprev, xtra.z, a1.z); a1.w = fmaf(wprev, xtra.w, a1.w);

    // ---- merge 16 half-wave states ----
    *(float4*)&sA0[idx][l5 * 4] = a0;
    *(float4*)&sA1[idx][l5 * 4] = a1;
    if (l5 == 0) { smx[idx] = mrun; sZ[idx] = Zrun; }
    __syncthreads();

    float gm = smx[0];
    #pragma unroll
    for (int k = 1; k < 16; ++k) gm = fmaxf(gm, smx[k]);
    float scl[16];
    float Gz = 0.f;
    #pragma unroll
    for (int k = 0; k < 16; ++k) { scl[k] = exp2f(smx[k] - gm); Gz = fmaf(scl[k], sZ[k], Gz); }

    if (tid < 128) {
        float acc = 0.f;
        #pragma unroll
        for (int k = 0; k < 16; ++k) acc = fmaf(scl[k], sA0[k][tid], acc);
        gA0[tid] = acc;
    } else if (tid < 256) {
        const int t = tid - 128;
        float acc = 0.f;
        #pragma unroll
        for (int k = 0; k < 16; ++k) acc = fmaf(scl[k], sA1[k][t], acc);
        gA1[t] = acc;
    }
    __syncthreads();

    // ---- embedding[o] = (w0[o,:]·A0 + w1[o,:]·A1)/Z + conv_b[o] ----
    if (tid < 128) {
        const float4* wr = (const float4*)(conv_w + tid * 256);
        float acc = 0.f;
        #pragma unroll 8
        for (int i = 0; i < 64; ++i) {
            float4 w4 = wr[i];   // w0[o,2i], w1[o,2i], w0[o,2i+1], w1[o,2i+1]
            acc = fmaf(w4.x, gA0[2 * i], acc);
            acc = fmaf(w4.y, gA1[2 * i], acc);
            acc = fmaf(w4.z, gA0[2 * i + 1], acc);
            acc = fmaf(w4.w, gA1[2 * i + 1], acc);
        }
        semb[tid] = acc / Gz + conv_b[tid];
    }
    __syncthreads();

    // ---- MLP layer 1 ----
    if (tid < 64) {
        const float* w1r = W1 + tid * (Nq + Mq);
        float acc = b1[tid];
        #pragma unroll 8
        for (int i = 0; i < 128; ++i) acc = fmaf(w1r[i], semb[i], acc);
        #pragma unroll 8
        for (int i = 0; i < 256; ++i) acc = fmaf(w1r[128 + i], szcol[i], acc);
        shb[tid] = fmaxf(acc, 0.f);
    }
    __syncthreads();

    // ---- MLP layer 2 + softmax over E ----
    if (tid < 64) {
        const float* w2r = W2 + tid * Eq;
        float acc = b2[tid];
        #pragma unroll 8
        for (int j = 0; j < 64; ++j) acc = fmaf(w2r[j], shb[j], acc);
        float v = -acc * (LOG2E / fabsf(temp2[0]));
        float mx = v;
        #pragma unroll
        for (int off = 32; off > 0; off >>= 1) mx = fmaxf(mx, __shfl_xor(mx, off, 64));
        float w = exp2f(v - mx);
        float s = w;
        #pragma unroll
        for (int off = 32; off > 0; off >>= 1) s += __shfl_xor(s, off, 64);
        out[tid * Bq + b] = w / s;
    }
}

extern "C" void kernel_launch(void* const* d_in, const int* in_sizes, int n_in,
                              void* d_out, int out_size, void* d_ws, size_t ws_size,
                              hipStream_t stream) {
    const float* context = (const float*)d_in[0];
    const float* z       = (const float*)d_in[1];
    const float* noise   = (const float*)d_in[2];
    const float* conv_w  = (const float*)d_in[3];
    const float* conv_b  = (const float*)d_in[4];
    const float* D       = (const float*)d_in[5];
    const float* sigma   = (const float*)d_in[6];
    const float* temp1   = (const float*)d_in[7];
    const float* W1      = (const float*)d_in[8];
    const float* b1      = (const float*)d_in[9];
    const float* W2      = (const float*)d_in[10];
    const float* b2      = (const float*)d_in[11];
    const float* temp2   = (const float*)d_in[12];
    float* out = (float*)d_out;

    gating_kernel<<<dim3(Bq), dim3(512), 0, stream>>>(
        context, z, noise, conv_w, conv_b, D, sigma, temp1,
        W1, b1, W2, b2, temp2, out);
}